// Round 19
// baseline (201.243 us; speedup 1.0000x reference)
//
#include <hip/hip_runtime.h>
#include <stdint.h>

// ---------------- problem constants (fixed by setup_inputs) ----------------
#define G       69
#define BATCH   8
// sparse_shape (Z,Y,X) = (32,512,512), window (12,12,32), SHIFT=true
// mwx = 44, mwy = 44, mwz = 2
#define MPS     3872        // 44*44*2
#define VOL     4608        // 12*12*32
#define VOLMPS  17842176    // VOL*MPS: key / VOLMPS = batch index
// max key = 142,737,407 < 1089*131072
#define NBUK    1089        // buckets per map: key>>17
#define NB2     2178        // both maps
#define B_WORDS 4096        // 2^17 bits per bucket / 32
#define BT      1024        // hist/bin block size
#define RT      512         // rank block size
#define NBLK    256         // point chunks
#define PAD     16          // 16 uints = 64 B: one cacheline per bucket counter

// ctrl layout (int32 indices)
#define C_COUNTS 0   // [8]
#define C_BS     8   // [9]
#define C_CP     17  // [8]
#define C_BSP    25  // [9]
#define C_DONE   34  // done-counter for hist's last-block scan fusion

// LDS bitmap XOR swizzle (rank): breaks the 2-bank pathology of
// 16-consecutive-word reads; involution within each 16-word block.
#define BSWZ(w) ((w) ^ (((w) >> 4) & 15))

__device__ __forceinline__ void keys_from_coord(int4 c, unsigned& kx, unsigned& ky) {
    int b  = c.x;
    int zz = c.y + 16;   // z + win_z/2
    int yy = c.z + 6;    // y + win_y/2
    int xx = c.w + 6;    // x + win_x/2
    int wx = xx / 12, cx = xx - wx*12;
    int wy = yy / 12, cy = yy - wy*12;
    int wz = zz >> 5, cz = zz & 31;
    int bwx = b*MPS + wx*88 + wy*2 + wz;   // mwy*mwz = 88
    int bwy = b*MPS + wy*88 + wx*2 + wz;   // mwx*mwz = 88
    kx = (unsigned)(bwx*VOL + cx*384 + cy*32 + cz);  // win_y*win_z = 384
    ky = (unsigned)(bwy*VOL + cy*384 + cx*32 + cz);  // win_x*win_z = 384
}

__device__ __forceinline__ unsigned wave_iscan(unsigned x, int lane) {
    #pragma unroll
    for (int d = 1; d < 64; d <<= 1) {
        unsigned u = __shfl_up(x, d, 64);
        if (lane >= d) x += u;
    }
    return x;
}

// ---------------- K1: LDS hist -> ONE padded atomic per (block,bucket) ->
//                      elected-last-block scan (recStart, cursor seed, prefixes) ----
// R3 evidence: same-line atomic RMW ~41cy serialized; 136 lines x 4096 RMWs = 70us.
// Padding each bucket to its own 64B line caps the serial chain at 256 RMWs (~4.4us).
__global__ __launch_bounds__(BT) void hist_kernel(const int4* __restrict__ coords, int N, int chunk,
                            int* __restrict__ ctrl,
                            unsigned* __restrict__ totalsPad,
                            unsigned* __restrict__ cursorPad,
                            unsigned* __restrict__ recStart) {
    __shared__ unsigned h[NB2];
    __shared__ int hb[BATCH];
    __shared__ int s_last;
    int t = threadIdx.x, blk = blockIdx.x;
    int lane = t & 63, wid = t >> 6;
    for (int k = t; k < NB2; k += BT) h[k] = 0u;
    if (t < BATCH) hb[t] = 0;
    __syncthreads();
    int start = blk * chunk;
    int end   = min(start + chunk, N);
    int c0=0,c1=0,c2=0,c3=0,c4=0,c5=0,c6=0,c7=0;
    for (int i = start + t; i < end; i += BT) {
        int4 c = coords[i];
        int b = c.x;
        c0 += (b==0); c1 += (b==1); c2 += (b==2); c3 += (b==3);
        c4 += (b==4); c5 += (b==5); c6 += (b==6); c7 += (b==7);
        unsigned kx, ky;
        keys_from_coord(c, kx, ky);
        atomicAdd(&h[kx >> 17], 1u);
        atomicAdd(&h[NBUK + (ky >> 17)], 1u);
    }
    if (c0) atomicAdd(&hb[0],c0);  if (c1) atomicAdd(&hb[1],c1);
    if (c2) atomicAdd(&hb[2],c2);  if (c3) atomicAdd(&hb[3],c3);
    if (c4) atomicAdd(&hb[4],c4);  if (c5) atomicAdd(&hb[5],c5);
    if (c6) atomicAdd(&hb[6],c6);  if (c7) atomicAdd(&hb[7],c7);
    __syncthreads();
    // one padded atomic per nonzero bucket: 2178 independent cachelines
    for (int k = t; k < NB2; k += BT) {
        unsigned v = h[k];
        if (v) atomicAdd(&totalsPad[(size_t)k * PAD], v);
    }
    if (t < BATCH && hb[t]) atomicAdd(&ctrl[C_COUNTS + t], hb[t]);

    // last-block election (threadFenceReduction pattern; proven R11/R16/R18)
    __threadfence();
    __syncthreads();
    if (t == 0) {
        int d = atomicAdd(&ctrl[C_DONE], 1);
        s_last = (d == (int)gridDim.x - 1);
    }
    __syncthreads();
    if (!s_last) return;

    // ---- bucket-total exclusive scan (BT=1024 threads, 3 rounds) ----
    __shared__ unsigned warpsum[BT/64];
    __shared__ unsigned s_carry;
    if (t == 0) s_carry = 0u;
    __syncthreads();
    for (int base = 0; base < NB2; base += BT) {
        int idx = base + t;
        unsigned v = (idx < NB2)
            ? __hip_atomic_load(&totalsPad[(size_t)idx * PAD], __ATOMIC_RELAXED, __HIP_MEMORY_SCOPE_AGENT) : 0u;
        unsigned x = wave_iscan(v, lane);
        if (lane == 63) warpsum[wid] = x;
        __syncthreads();
        if (wid == 0) {
            unsigned v2 = (lane < BT/64) ? warpsum[lane] : 0u;
            unsigned x2 = wave_iscan(v2, lane);
            if (lane < BT/64) warpsum[lane] = x2;
        }
        __syncthreads();
        unsigned excl = s_carry + (wid ? warpsum[wid-1] : 0u) + x - v;
        unsigned roundTot = warpsum[BT/64 - 1];
        if (idx < NB2) { recStart[idx] = excl; cursorPad[(size_t)idx * PAD] = excl; }
        __syncthreads();
        if (t == 0) s_carry += roundTot;
        __syncthreads();
    }
    if (t == 0) {
        recStart[NB2] = s_carry;   // == 2N
        int bs = 0, bsp = 0;
        ctrl[C_BS] = 0; ctrl[C_BSP] = 0;
        for (int b = 0; b < BATCH; b++) {
            int n  = __hip_atomic_load(&ctrl[C_COUNTS + b], __ATOMIC_RELAXED, __HIP_MEMORY_SCOPE_AGENT);
            int np = ((n + G - 1) / G) * G;
            ctrl[C_CP + b] = np;
            bs += n; bsp += np;
            ctrl[C_BS + b + 1]  = bs;
            ctrl[C_BSP + b + 1] = bsp;
        }
    }
}

// ---------------- K2: two-pass binning; padded-atomic range reservation ----------------
// Keys cached in registers across passes (chunk <= 8*BT). Within-bucket order is
// irrelevant (rank orders by unique keys), so block ranges may land in any order.
__global__ __launch_bounds__(BT) void bin_kernel(const int4* __restrict__ coords, int N, int chunk, int Np,
                           const int* __restrict__ ctrl,
                           unsigned* __restrict__ cursorPad,
                           uint2* __restrict__ rec,
                           int* __restrict__ w2f,
                           int* __restrict__ f2w) {
    __shared__ unsigned h[NB2];
    __shared__ int s_off[BATCH];
    __shared__ int s_bs[BATCH+1], s_bsp[BATCH+1], s_cnt[BATCH], s_cp[BATCH];
    int t = threadIdx.x, blk = blockIdx.x;
    for (int k = t; k < NB2; k += BT) h[k] = 0u;
    if (t < BATCH) {
        s_off[t] = ctrl[C_BSP+t] - ctrl[C_BS+t];
        s_cnt[t] = ctrl[C_COUNTS+t];
        s_cp[t]  = ctrl[C_CP+t];
    }
    if (t < BATCH+1) { s_bs[t] = ctrl[C_BS+t]; s_bsp[t] = ctrl[C_BSP+t]; }
    __syncthreads();
    int start = blk * chunk;
    int end   = min(start + chunk, N);
    // pass 1: load coords once, keep keys in registers
    unsigned kxA[8], kyA[8];
    #pragma unroll
    for (int it = 0; it < 8; ++it) {
        int i = start + it*BT + t;
        kxA[it] = 0u; kyA[it] = 0u;
        if (i < end) {
            int4 c = coords[i];
            unsigned kx, ky;
            keys_from_coord(c, kx, ky);
            kxA[it] = kx; kyA[it] = ky;
            atomicAdd(&h[kx >> 17], 1u);
            atomicAdd(&h[NBUK + (ky >> 17)], 1u);
        }
    }
    __syncthreads();
    // reserve contiguous per-bucket ranges: one padded atomic per (block,bucket)
    for (int k = t; k < NB2; k += BT) {
        unsigned c = h[k];
        h[k] = c ? atomicAdd(&cursorPad[(size_t)k * PAD], c) : 0u;
    }
    __syncthreads();
    // pass 2: scatter from registers
    #pragma unroll
    for (int it = 0; it < 8; ++it) {
        int i = start + it*BT + t;
        if (i < end) {
            unsigned kx = kxA[it], ky = kyA[it];
            int b = (int)(kx / VOLMPS);          // recover batch from key
            w2f[i] = i + s_off[b];
            unsigned px = atomicAdd(&h[kx >> 17], 1u);
            rec[px] = make_uint2(kx, (unsigned)i);
            unsigned py = atomicAdd(&h[NBUK + (ky >> 17)], 1u);
            rec[py] = make_uint2(ky, (unsigned)i);
        }
    }
    // fused flat2win (closed form over padded index space)
    int gs = (int)gridDim.x * BT;
    for (int j = blk*BT + t; j < Np; j += gs) {
        int b = 0;
        #pragma unroll
        for (int k = 1; k < BATCH; k++) b += (j >= s_bsp[k]);
        int off  = s_bsp[b] - s_bs[b];
        int num  = s_cnt[b], nump = s_cp[b];
        int r    = num % G;
        int tail_start = (num != nump) ? (s_bsp[b+1] - G + r) : s_bsp[b+1];
        int v;
        if (j < tail_start)       v = j - off;
        else if (nump != G)       v = j - G - off;
        else { int tt = j - tail_start; int m = num > 0 ? num : 1; v = s_bs[b] + tt % m; }
        f2w[j] = v;
    }
}

// ---------------- K3: per-bucket bitmap rank (unchanged, measured good) ----------------
__global__ __launch_bounds__(RT) void rank_kernel(const uint2* __restrict__ rec,
                            const unsigned* __restrict__ recStart, int N,
                            int* __restrict__ xmap, int* __restrict__ ymap) {
    int b = blockIdx.x;                      // 0..NB2-1
    unsigned start = recStart[b], end = recStart[b+1];
    int cnt = (int)(end - start);
    if (cnt == 0) return;                    // uniform across block
    int map = (b >= NBUK);
    __shared__ unsigned bits[B_WORDS];       // 16 KB
    __shared__ unsigned short pref[B_WORDS]; // 8 KB (max prefix ~2100 fits u16)
    __shared__ unsigned wsum[RT/64];
    int t = threadIdx.x;
    #pragma unroll
    for (int k = 0; k < B_WORDS/RT; k++) bits[t + RT*k] = 0u;
    __syncthreads();
    // pass 1: build the key bitmap
    for (int j = t; j < cnt; j += RT) {
        unsigned key = rec[start + j].x;
        unsigned local = key & 131071u;
        atomicOr(&bits[BSWZ(local >> 5)], 1u << (local & 31));
    }
    __syncthreads();
    int base = t * (B_WORDS/RT);             // 8 logical words per thread
    unsigned w[B_WORDS/RT];
    unsigned s = 0;
    #pragma unroll
    for (int k = 0; k < B_WORDS/RT; k++) { w[k] = bits[BSWZ(base + k)]; s += __popc(w[k]); }
    int lane = t & 63, wid = t >> 6;
    unsigned x = wave_iscan(s, lane);
    if (lane == 63) wsum[wid] = x;
    __syncthreads();
    unsigned add = 0;
    #pragma unroll
    for (int q = 0; q < RT/64 - 1; q++) add += (wid > q) ? wsum[q] : 0u;
    unsigned excl = add + x - s;
    #pragma unroll
    for (int k = 0; k < B_WORDS/RT; k++) {
        pref[BSWZ(base + k)] = (unsigned short)excl;
        excl += __popc(w[k]);
    }
    __syncthreads();
    // pass 2: re-read rec (L3-resident; just written by bin) and scatter ranks
    int* __restrict__ out = map ? ymap : xmap;
    unsigned rankBase = start - (map ? (unsigned)N : 0u);
    for (int j = t; j < cnt; j += RT) {
        uint2 r = rec[start + j];
        unsigned local = r.x & 131071u;
        unsigned wd = local >> 5, bt = local & 31u;
        unsigned sw = BSWZ(wd);
        unsigned rank = rankBase + (unsigned)pref[sw] + __popc(bits[sw] & ((1u << bt) - 1u));
        out[rank] = (int)r.y;
    }
}

// ---------------- launch ----------------
extern "C" void kernel_launch(void* const* d_in, const int* in_sizes, int n_in,
                              void* d_out, int out_size, void* d_ws, size_t ws_size,
                              hipStream_t stream) {
    const int* coords = (const int*)d_in[0];
    int N  = in_sizes[0] / 4;
    int Np = out_size - 3 * N;
    int chunk = (N + NBLK - 1) / NBLK;   // ~7818 <= 8*BT (bin register cache)

    char* ws = (char*)d_ws;
    int*      ctrl      = (int*)(ws + 0);               // 256 B
    unsigned* recStart  = (unsigned*)(ws + 256);        // (NB2+1)*4 = 8716 -> ends 8972
    unsigned* totalsPad = (unsigned*)(ws + 9216);       // NB2*64 B = 139,392 -> ends 148,608
    unsigned* cursorPad = (unsigned*)(ws + 148608);     // NB2*64 B           -> ends 288,000
    uint2*    rec       = (uint2*)(ws + 288000);        // 2N*8 B (~32 MB)

    int* out  = (int*)d_out;
    int* f2w  = out;
    int* w2f  = out + Np;
    int* xmap = out + Np + N;
    int* ymap = out + Np + 2*N;

    hipMemsetAsync(ws, 0, 288000, stream);   // ctrl + recStart + totalsPad + cursorPad

    hist_kernel<<<NBLK, BT, 0, stream>>>((const int4*)coords, N, chunk, ctrl, totalsPad, cursorPad, recStart);
    bin_kernel<<<NBLK, BT, 0, stream>>>((const int4*)coords, N, chunk, Np, ctrl, cursorPad, rec, w2f, f2w);
    rank_kernel<<<NB2, RT, 0, stream>>>(rec, recStart, N, xmap, ymap);
}

// Round 20
// 143.578 us; speedup vs baseline: 1.4016x; 1.4016x over previous
//
#include <hip/hip_runtime.h>
#include <stdint.h>

// ---------------- problem constants (fixed by setup_inputs) ----------------
#define G       69
#define BATCH   8
// sparse_shape (Z,Y,X) = (32,512,512), window (12,12,32), SHIFT=true
// mwx = 44, mwy = 44, mwz = 2
#define MPS     3872        // 44*44*2
#define VOL     4608        // 12*12*32
// max key = 142,737,407 < 1089*131072
#define NBUK    1089        // buckets per map: key>>17
#define NB2     2178        // both maps
#define B_WORDS 4096        // 2^17 bits per bucket / 32
#define BT      1024        // hist/bin block size
#define CT      1024        // colscan block size (16 waves)
#define CBLK    35          // ceil(NB2 / 64 columns per block)
#define ST      1024        // scan block size
#define RT      512         // rank block size
#define NBLK    256         // point chunks

// ctrl layout (int32 indices)
#define C_COUNTS 0   // [8]
#define C_BS     8   // [9]
#define C_CP     17  // [8]
#define C_BSP    25  // [9]

// LDS bitmap XOR swizzle (rank): breaks the 2-bank pathology of
// 16-consecutive-word reads; involution within each 16-word block.
#define BSWZ(w) ((w) ^ (((w) >> 4) & 15))

__device__ __forceinline__ void keys_from_coord(int4 c, unsigned& kx, unsigned& ky) {
    int b  = c.x;
    int zz = c.y + 16;   // z + win_z/2
    int yy = c.z + 6;    // y + win_y/2
    int xx = c.w + 6;    // x + win_x/2
    int wx = xx / 12, cx = xx - wx*12;
    int wy = yy / 12, cy = yy - wy*12;
    int wz = zz >> 5, cz = zz & 31;
    int bwx = b*MPS + wx*88 + wy*2 + wz;   // mwy*mwz = 88
    int bwy = b*MPS + wy*88 + wx*2 + wz;   // mwx*mwz = 88
    kx = (unsigned)(bwx*VOL + cx*384 + cy*32 + cz);  // win_y*win_z = 384
    ky = (unsigned)(bwy*VOL + cy*384 + cx*32 + cz);  // win_x*win_z = 384
}

__device__ __forceinline__ unsigned wave_iscan(unsigned x, int lane) {
    #pragma unroll
    for (int d = 1; d < 64; d <<= 1) {
        unsigned u = __shfl_up(x, d, 64);
        if (lane >= d) x += u;
    }
    return x;
}

// ---------------- K1: per-chunk LDS histogram -> coalesced row store ----------------
// NO fence, NO device atomics except 8 batch counters. Visibility to later
// dispatches is stream-ordered (proven since R11).
__global__ __launch_bounds__(BT) void hist_kernel(const int4* __restrict__ coords, int N, int chunk,
                            int* __restrict__ ctrl, unsigned* __restrict__ histMat) {
    __shared__ unsigned h[NB2];
    __shared__ int hb[BATCH];
    int t = threadIdx.x, blk = blockIdx.x;
    for (int k = t; k < NB2; k += BT) h[k] = 0u;
    if (t < BATCH) hb[t] = 0;
    __syncthreads();
    int start = blk * chunk;
    int end   = min(start + chunk, N);
    int c0=0,c1=0,c2=0,c3=0,c4=0,c5=0,c6=0,c7=0;
    for (int i = start + t; i < end; i += BT) {
        int4 c = coords[i];
        int b = c.x;
        c0 += (b==0); c1 += (b==1); c2 += (b==2); c3 += (b==3);
        c4 += (b==4); c5 += (b==5); c6 += (b==6); c7 += (b==7);
        unsigned kx, ky;
        keys_from_coord(c, kx, ky);
        atomicAdd(&h[kx >> 17], 1u);
        atomicAdd(&h[NBUK + (ky >> 17)], 1u);
    }
    if (c0) atomicAdd(&hb[0],c0);  if (c1) atomicAdd(&hb[1],c1);
    if (c2) atomicAdd(&hb[2],c2);  if (c3) atomicAdd(&hb[3],c3);
    if (c4) atomicAdd(&hb[4],c4);  if (c5) atomicAdd(&hb[5],c5);
    if (c6) atomicAdd(&hb[6],c6);  if (c7) atomicAdd(&hb[7],c7);
    __syncthreads();
    // coalesced row write (plain stores)
    for (int k = t; k < NB2; k += BT) histMat[(size_t)blk * NB2 + k] = h[k];
    if (t < BATCH && hb[t]) atomicAdd(&ctrl[C_COUNTS + t], hb[t]);
}

// ---------------- K2: coalesced two-pass column scan (64 cols/block, 16 waves) ----
// R18 layout (lanes on consecutive columns -> every access one 256B wave txn;
// waves on row groups; LDS part[16][64] inter-wave scan) MINUS fence/election.
__global__ __launch_bounds__(CT) void colscan_kernel(unsigned* __restrict__ histMat,
                               unsigned* __restrict__ totals) {
    __shared__ unsigned part[16][64];
    int t = threadIdx.x;
    int lane = t & 63, wid = t >> 6;
    int col = blockIdx.x * 64 + lane;
    unsigned v[16];
    unsigned s = 0;
    if (col < NB2) {
        #pragma unroll
        for (int u = 0; u < 16; u++) v[u] = histMat[(size_t)(wid*16 + u) * NB2 + col];
        #pragma unroll
        for (int u = 0; u < 16; u++) s += v[u];
    }
    part[wid][lane] = s;
    __syncthreads();
    // per-column exclusive scan over the 16 wave-partials (wave 0, serial-16 LDS)
    if (wid == 0) {
        unsigned run = 0;
        #pragma unroll
        for (int w = 0; w < 16; w++) {
            unsigned tmp = part[w][lane];
            part[w][lane] = run;
            run += tmp;
        }
        if (col < NB2) totals[col] = run;   // column total
    }
    __syncthreads();
    if (col < NB2) {
        unsigned excl = part[wid][lane];
        #pragma unroll
        for (int u = 0; u < 16; u++) {
            histMat[(size_t)(wid*16 + u) * NB2 + col] = excl;
            excl += v[u];
        }
    }
}

// ---------------- K3: 1-block bucket-total scan -> recStart; batch prefixes ----------------
// Single block, stream-ordered inputs: no fence needed anywhere.
__global__ __launch_bounds__(ST) void scan_kernel(int* __restrict__ ctrl,
                            const unsigned* __restrict__ totals,
                            unsigned* __restrict__ recStart) {
    __shared__ unsigned warpsum[ST/64];
    __shared__ unsigned s_carry;
    int t = threadIdx.x;
    int lane = t & 63, wid = t >> 6;
    if (t == 0) s_carry = 0u;
    __syncthreads();
    for (int base = 0; base < NB2; base += ST) {
        int idx = base + t;
        unsigned v = (idx < NB2) ? totals[idx] : 0u;
        unsigned x = wave_iscan(v, lane);
        if (lane == 63) warpsum[wid] = x;
        __syncthreads();
        if (wid == 0) {
            unsigned v2 = (lane < ST/64) ? warpsum[lane] : 0u;
            unsigned x2 = wave_iscan(v2, lane);
            if (lane < ST/64) warpsum[lane] = x2;
        }
        __syncthreads();
        unsigned excl = s_carry + (wid ? warpsum[wid-1] : 0u) + x - v;
        unsigned roundTot = warpsum[ST/64 - 1];
        if (idx < NB2) recStart[idx] = excl;
        __syncthreads();
        if (t == 0) s_carry += roundTot;
        __syncthreads();
    }
    if (t == 0) {
        recStart[NB2] = s_carry;   // == 2N
        int bs = 0, bsp = 0;
        ctrl[C_BS] = 0; ctrl[C_BSP] = 0;
        for (int b = 0; b < BATCH; b++) {
            int n  = ctrl[C_COUNTS + b];
            int np = ((n + G - 1) / G) * G;
            ctrl[C_CP + b] = np;
            bs += n; bsp += np;
            ctrl[C_BS + b + 1]  = bs;
            ctrl[C_BSP + b + 1] = bsp;
        }
    }
}

// ---------------- K4: contention-free binning via LDS cursors (no global atomics)
//                      + win2flat + fused flat2win ----------------
__global__ __launch_bounds__(BT) void bin_kernel(const int4* __restrict__ coords, int N, int chunk, int Np,
                           const int* __restrict__ ctrl,
                           const unsigned* __restrict__ recStart,
                           const unsigned* __restrict__ histMat,
                           uint2* __restrict__ rec,
                           int* __restrict__ w2f,
                           int* __restrict__ f2w) {
    __shared__ unsigned cur[NB2];
    __shared__ int s_off[BATCH];
    __shared__ int s_bs[BATCH+1], s_bsp[BATCH+1], s_cnt[BATCH], s_cp[BATCH];
    int t = threadIdx.x, blk = blockIdx.x;
    if (t < BATCH) {
        s_off[t] = ctrl[C_BSP+t] - ctrl[C_BS+t];
        s_cnt[t] = ctrl[C_COUNTS+t];
        s_cp[t]  = ctrl[C_CP+t];
    }
    if (t < BATCH+1) { s_bs[t] = ctrl[C_BS+t]; s_bsp[t] = ctrl[C_BSP+t]; }
    // seed per-block bucket cursors: recStart + exclusive-scanned histMat row
    for (int k = t; k < NB2; k += BT)
        cur[k] = recStart[k] + histMat[(size_t)blk * NB2 + k];
    __syncthreads();
    int start = blk * chunk;
    int end   = min(start + chunk, N);
    for (int i = start + t; i < end; i += BT) {
        int4 c = coords[i];
        w2f[i] = i + s_off[c.x];
        unsigned kx, ky;
        keys_from_coord(c, kx, ky);
        unsigned px = atomicAdd(&cur[kx >> 17], 1u);
        rec[px] = make_uint2(kx, (unsigned)i);
        unsigned py = atomicAdd(&cur[NBUK + (ky >> 17)], 1u);
        rec[py] = make_uint2(ky, (unsigned)i);
    }
    // fused flat2win (closed form over padded index space)
    int gs = (int)gridDim.x * BT;
    for (int j = blk*BT + t; j < Np; j += gs) {
        int b = 0;
        #pragma unroll
        for (int k = 1; k < BATCH; k++) b += (j >= s_bsp[k]);
        int off  = s_bsp[b] - s_bs[b];
        int num  = s_cnt[b], nump = s_cp[b];
        int r    = num % G;
        int tail_start = (num != nump) ? (s_bsp[b+1] - G + r) : s_bsp[b+1];
        int v;
        if (j < tail_start)       v = j - off;
        else if (nump != G)       v = j - G - off;
        else { int tt = j - tail_start; int m = num > 0 ? num : 1; v = s_bs[b] + tt % m; }
        f2w[j] = v;
    }
}

// ---------------- K5: per-bucket bitmap rank (unchanged, measured good) ----------------
__global__ __launch_bounds__(RT) void rank_kernel(const uint2* __restrict__ rec,
                            const unsigned* __restrict__ recStart, int N,
                            int* __restrict__ xmap, int* __restrict__ ymap) {
    int b = blockIdx.x;                      // 0..NB2-1
    unsigned start = recStart[b], end = recStart[b+1];
    int cnt = (int)(end - start);
    if (cnt == 0) return;                    // uniform across block
    int map = (b >= NBUK);
    __shared__ unsigned bits[B_WORDS];       // 16 KB
    __shared__ unsigned short pref[B_WORDS]; // 8 KB (max prefix ~2100 fits u16)
    __shared__ unsigned wsum[RT/64];
    int t = threadIdx.x;
    #pragma unroll
    for (int k = 0; k < B_WORDS/RT; k++) bits[t + RT*k] = 0u;
    __syncthreads();
    // pass 1: build the key bitmap
    for (int j = t; j < cnt; j += RT) {
        unsigned key = rec[start + j].x;
        unsigned local = key & 131071u;
        atomicOr(&bits[BSWZ(local >> 5)], 1u << (local & 31));
    }
    __syncthreads();
    int base = t * (B_WORDS/RT);             // 8 logical words per thread
    unsigned w[B_WORDS/RT];
    unsigned s = 0;
    #pragma unroll
    for (int k = 0; k < B_WORDS/RT; k++) { w[k] = bits[BSWZ(base + k)]; s += __popc(w[k]); }
    int lane = t & 63, wid = t >> 6;
    unsigned x = wave_iscan(s, lane);
    if (lane == 63) wsum[wid] = x;
    __syncthreads();
    unsigned add = 0;
    #pragma unroll
    for (int q = 0; q < RT/64 - 1; q++) add += (wid > q) ? wsum[q] : 0u;
    unsigned excl = add + x - s;
    #pragma unroll
    for (int k = 0; k < B_WORDS/RT; k++) {
        pref[BSWZ(base + k)] = (unsigned short)excl;
        excl += __popc(w[k]);
    }
    __syncthreads();
    // pass 2: re-read rec (L3-resident; just written by bin) and scatter ranks
    int* __restrict__ out = map ? ymap : xmap;
    unsigned rankBase = start - (map ? (unsigned)N : 0u);
    for (int j = t; j < cnt; j += RT) {
        uint2 r = rec[start + j];
        unsigned local = r.x & 131071u;
        unsigned wd = local >> 5, bt = local & 31u;
        unsigned sw = BSWZ(wd);
        unsigned rank = rankBase + (unsigned)pref[sw] + __popc(bits[sw] & ((1u << bt) - 1u));
        out[rank] = (int)r.y;
    }
}

// ---------------- launch ----------------
extern "C" void kernel_launch(void* const* d_in, const int* in_sizes, int n_in,
                              void* d_out, int out_size, void* d_ws, size_t ws_size,
                              hipStream_t stream) {
    const int* coords = (const int*)d_in[0];
    int N  = in_sizes[0] / 4;
    int Np = out_size - 3 * N;
    int chunk = (N + NBLK - 1) / NBLK;

    char* ws = (char*)d_ws;
    int*      ctrl     = (int*)(ws + 0);              // 256 B
    unsigned* totals   = (unsigned*)(ws + 256);       // NB2*4          -> ends 8968
    unsigned* recStart = (unsigned*)(ws + 8968);      // (NB2+1)*4      -> ends 17684
    unsigned* histMat  = (unsigned*)(ws + 17696);     // 256*2178*4 = 2,230,272 -> ends 2,247,968
    uint2*    rec      = (uint2*)(ws + 2247968);      // 2N*8 B (~32 MB)

    int* out  = (int*)d_out;
    int* f2w  = out;
    int* w2f  = out + Np;
    int* xmap = out + Np + N;
    int* ymap = out + Np + 2*N;

    hipMemsetAsync(ctrl, 0, 256, stream);

    hist_kernel<<<NBLK, BT, 0, stream>>>((const int4*)coords, N, chunk, ctrl, histMat);
    colscan_kernel<<<CBLK, CT, 0, stream>>>(histMat, totals);
    scan_kernel<<<1, ST, 0, stream>>>(ctrl, totals, recStart);
    bin_kernel<<<NBLK, BT, 0, stream>>>((const int4*)coords, N, chunk, Np, ctrl, recStart, histMat, rec, w2f, f2w);
    rank_kernel<<<NB2, RT, 0, stream>>>(rec, recStart, N, xmap, ymap);
}